// Round 1
// baseline (214.595 us; speedup 1.0000x reference)
//
#include <hip/hip_runtime.h>
#include <hip/hip_bf16.h>
#include <math.h>

// Problem constants
#define LQ 196      // spatial tokens (14x14)
#define NH 12       // heads
#define DH 64       // head dim
#define CC 768      // output channels
#define NPAIR 28    // 4 n * 7 t' pairs per half
#define PQ ((size_t)LQ * LQ)   // 38416
#define NW 729      // (2*14-1)^2 w rows

#define KROWS2 224  // 14*16 (k padded so both k-halves run 7 uniform tiles)
#define LPITCH 72   // shorts per Ks LDS row (64 + 8 pad)
#define APITCH 232  // out-kernel A LDS pitch

// ws layout (in shorts): Pm | Wb   (Qb/Kb eliminated — attn reads f32 direct)
#define PM_SHORTS ((size_t)2 * NPAIR * PQ)
#define WB_OFF    PM_SHORTS

typedef short short8 __attribute__((ext_vector_type(8)));
typedef float f32x4  __attribute__((ext_vector_type(4)));

__device__ __forceinline__ short f2bf(float f) {
    __hip_bfloat16 h = __float2bfloat16(f);
    return __builtin_bit_cast(short, h);
}

__device__ __forceinline__ short8 cvt8(float4 a, float4 b) {
    short8 r;
    r[0] = f2bf(a.x); r[1] = f2bf(a.y); r[2] = f2bf(a.z); r[3] = f2bf(a.w);
    r[4] = f2bf(b.x); r[5] = f2bf(b.y); r[6] = f2bf(b.z); r[7] = f2bf(b.w);
    return r;
}

// ---------------------------------------------------------------------------
// ATTN fused over heads, DOUBLE-BUFFERED, now reading Q/K f32 DIRECTLY
// (prep's Q/K->bf16 pass eliminated: conversion happens in registers at the
// LDS-commit point; ~70 MB HBM traffic + one launch saved). Also carries the
// residual prep work: W1/W2 -> bf16 and zeroing the l=0 output rows (both
// consumed only by the out kernel, which launches after us).
// XCD swizzle: all 7 q-group blocks of a plane share blockIdx%8 -> same XCD
// -> K f32 hot-set ~1.2 MB fits 4 MB L2.
__global__ __launch_bounds__(256) void attn_fused_kernel(
    const float* __restrict__ Q, const float* __restrict__ K,
    const float* __restrict__ W1, const float* __restrict__ W2,
    short* __restrict__ Wb, short* __restrict__ Pm, float* __restrict__ Out)
{
    int bid = blockIdx.x, tid = threadIdx.x;

    // --- folded prep: W -> bf16 (3 quads/thread) + zero Out l=0 rows ---
    {
        int gid = bid * 256 + tid;                    // < 100352
        const int N4 = NW * CC / 4;                   // 139968
        for (int e4 = gid; e4 < 2 * N4; e4 += 392 * 256) {
            const float* src = (e4 < N4) ? (W1 + (size_t)e4 * 4)
                                         : (W2 + (size_t)(e4 - N4) * 4);
            float4 f = *(const float4*)src;
            short4 v = {f2bf(f.x), f2bf(f.y), f2bf(f.z), f2bf(f.w)};
            *(short4*)(Wb + (size_t)e4 * 4) = v;
        }
        if (gid < 32 * CC)
            Out[(size_t)(gid / CC) * 197 * CC + (gid % CC)] = 0.f;
    }

    int xcd  = bid & 7;
    int slot = bid >> 3;
    int plane = xcd + 8 * (slot / 7);    // 0..55 = hf*28 + p
    int qg    = slot % 7;
    int p  = plane % NPAIR;
    int hf = plane / NPAIR;              // 0: (q[t+1],k[t])  1: (q[t],k[t+1])
    int n = p / 7, i = p % 7;
    int tq = hf ? i     : i + 1;
    int tk = hf ? i + 1 : i;

    __shared__ __align__(16) short Ks[2][KROWS2 * LPITCH];  // 64.5 KB
    __shared__ __align__(16) short Ps[32 * LQ];             // 12.25 KB
    __shared__ float red[2][2][2][16];                      // [h&1][strip][khalf][row]

    int wave = tid >> 6, lane = tid & 63;
    int m16  = lane & 15, q4 = lane >> 4;
    int strip = wave >> 1, khalf = wave & 1;
    int tb = khalf * 7;                  // wave's k-tile base

    // f32 bases at l=1 (row stride NH*DH = 768 floats, head stride 64)
    const float* Qf = Q + (size_t)((n * 8 + tq) * 197 + 1) * (NH * DH);
    const float* Kf = K + (size_t)((n * 8 + tk) * 197 + 1) * (NH * DH);

    int qrow = qg * 32 + strip * 16 + m16;
    int qr = (qrow < LQ) ? qrow : (LQ - 1);   // clamp; rows >=196 never stored
    const float* qbase = Qf + (size_t)qr * (NH * DH) + q4 * 8;

    // per-thread staging geometry: e = tid + 256*j
    // src row r stride = 768 f32 (heads interleaved); LDS row = LPITCH shorts
    int srf[7], sw[7];  bool sv[7];
#pragma unroll
    for (int j = 0; j < 7; ++j) {
        int e = tid + 256 * j;
        int r = e >> 3, c8 = e & 7;
        srf[j] = r * (NH * DH) + c8 * 8;     // f32 element offset from head base
        sw[j]  = r * LPITCH + c8 * 8;        // LDS offset (shorts)
        sv[j]  = (r < LQ);
    }

    float4 z4 = {0.f, 0.f, 0.f, 0.f};
    // stage h=0 (f32 load -> bf16 convert -> LDS)
#pragma unroll
    for (int j = 0; j < 7; ++j) {
        float4 a = sv[j] ? *(const float4*)(Kf + srf[j])     : z4;
        float4 b = sv[j] ? *(const float4*)(Kf + srf[j] + 4) : z4;
        *(short8*)&Ks[0][sw[j]] = cvt8(a, b);
    }
    short8 qa0 = cvt8(*(const float4*)(qbase),      *(const float4*)(qbase + 4));
    short8 qa1 = cvt8(*(const float4*)(qbase + 32), *(const float4*)(qbase + 36));
    __syncthreads();

    f32x4 pm[7];
#pragma unroll
    for (int t = 0; t < 7; ++t) pm[t] = (f32x4){0.f, 0.f, 0.f, 0.f};

    for (int h = 0; h < NH; ++h) {
        int cur = h & 1;

        // prefetch next head (f32) into VGPRs (overlaps compute below)
        float4 pfa[7], pfb[7], qn0a, qn0b, qn1a, qn1b;
        if (h < NH - 1) {
            const float* kn = Kf + (size_t)(h + 1) * DH;
#pragma unroll
            for (int j = 0; j < 7; ++j) {
                pfa[j] = sv[j] ? *(const float4*)(kn + srf[j])     : z4;
                pfb[j] = sv[j] ? *(const float4*)(kn + srf[j] + 4) : z4;
            }
            const float* qn = qbase + (size_t)(h + 1) * DH;
            qn0a = *(const float4*)(qn);
            qn0b = *(const float4*)(qn + 4);
            qn1a = *(const float4*)(qn + 32);
            qn1b = *(const float4*)(qn + 36);
        }

        // MFMA on current buffer
        f32x4 acc[7];
#pragma unroll
        for (int t = 0; t < 7; ++t) acc[t] = (f32x4){0.f, 0.f, 0.f, 0.f};
#pragma unroll
        for (int t = 0; t < 7; ++t) {
            const short* kp = &Ks[cur][((tb + t) * 16 + m16) * LPITCH + q4 * 8];
            short8 b0 = *(const short8*)(kp);
            short8 b1 = *(const short8*)(kp + 32);
            acc[t] = __builtin_amdgcn_mfma_f32_16x16x32_bf16(qa0, b0, acc[t], 0, 0, 0);
            acc[t] = __builtin_amdgcn_mfma_f32_16x16x32_bf16(qa1, b1, acc[t], 0, 0, 0);
        }

        // exp (no max-sub: logits ~N(0,1)) + wave-partial row sums
        float v4[4] = {0.f, 0.f, 0.f, 0.f};
#pragma unroll
        for (int t = 0; t < 7; ++t) {
            int k = (tb + t) * 16 + m16;
#pragma unroll
            for (int r = 0; r < 4; ++r) {
                float pe = (k < LQ) ? __expf(acc[t][r] * 0.125f) : 0.f;
                acc[t][r] = pe;
                v4[r] += pe;
            }
        }
#pragma unroll
        for (int r = 0; r < 4; ++r) {
            v4[r] += __shfl_xor(v4[r], 1, 64);
            v4[r] += __shfl_xor(v4[r], 2, 64);
            v4[r] += __shfl_xor(v4[r], 4, 64);
            v4[r] += __shfl_xor(v4[r], 8, 64);
        }
        if (m16 == 0) {
#pragma unroll
            for (int r = 0; r < 4; ++r) red[cur][strip][khalf][q4 * 4 + r] = v4[r];
        }

        // commit prefetch: vmcnt wait inserted here by compiler, then convert
        // in-reg and write the other buffer
        if (h < NH - 1) {
#pragma unroll
            for (int j = 0; j < 7; ++j)
                *(short8*)&Ks[1 - cur][sw[j]] = cvt8(pfa[j], pfb[j]);
        }
        __syncthreads();
        // safe: all Ks[cur] reads happened before this barrier; next head's
        // writes to Ks[cur] occur after it. red[cur] read below; next head
        // writes red[1-cur].

        float inv[4];
#pragma unroll
        for (int r = 0; r < 4; ++r)
            inv[r] = 1.0f / (12.0f * (red[cur][strip][0][q4 * 4 + r] +
                                      red[cur][strip][1][q4 * 4 + r]));
#pragma unroll
        for (int t = 0; t < 7; ++t)
#pragma unroll
            for (int r = 0; r < 4; ++r) pm[t][r] += acc[t][r] * inv[r];

        if (h < NH - 1) { qa0 = cvt8(qn0a, qn0b); qa1 = cvt8(qn1a, qn1b); }
    }

    // epilogue: pm -> Ps strip -> linear coalesced stores
#pragma unroll
    for (int t = 0; t < 7; ++t) {
        int k = (tb + t) * 16 + m16;
        if (k < LQ) {
#pragma unroll
            for (int r = 0; r < 4; ++r)
                Ps[(strip * 16 + q4 * 4 + r) * LQ + k] = f2bf(pm[t][r]);
        }
    }
    __syncthreads();

    int row0 = qg * 32;
    int rows = LQ - row0; if (rows > 32) rows = 32;    // qg=6 -> 4 rows
    int nb = rows * (LQ * 2);                          // bytes, mult of 16
    char* dst = (char*)(Pm + (size_t)plane * PQ + (size_t)row0 * LQ);
    const char* sp = (const char*)Ps;
    for (int e = tid * 16; e < nb; e += 256 * 16)
        *(short8*)(dst + e) = *(const short8*)(sp + e);
}

// ---------------------------------------------------------------------------
// OUT (MFMA): per q: Out[n*8+t][c] = sum_k A1[n*7+t-1][q][k]*W1[idx(q,k)][c]
//                                  + sum_k A2[n*7+t  ][q][k]*W2[idx(q,k)][c]
// T-shifted A staging (M=32, one acc set); B gathered from bf16 Wb via
// premultiplied LDS idx table. grid (196, 4): y = c-quarter (12 tiles of 16,
// 3 per wave).
__global__ __launch_bounds__(256) void out_mfma_kernel(
    const short* __restrict__ Pm, const short* __restrict__ Wb,
    float* __restrict__ Out)
{
    int q   = blockIdx.x;
    int yb  = blockIdx.y;
    int tid = threadIdx.x;
    int wave = tid >> 6, lane = tid & 63;
    int n16 = lane & 15, q4 = lane >> 4;

    __shared__ __align__(16) short A1s[32 * APITCH];   // 14.8 KB
    __shared__ __align__(16) short A2s[32 * APITCH];
    __shared__ int idxs[224];                          // premultiplied by CC

    const short* Wb1 = Wb;
    const short* Wb2 = Wb + (size_t)NW * CC;

    int pi = q / 14, pj = q % 14;
    for (int k = tid; k < 224; k += 256) {
        int v = 0;
        if (k < LQ) { int ki = k / 14, kj = k % 14; v = (pi - ki + 13) * 27 + (pj - kj + 13); }
        idxs[k] = v * CC;
    }

    // A staging: 64 rows x 58 short4 slots (APITCH=232)
    for (int e = tid; e < 64 * 58; e += 256) {
        int r2 = e / 58, c4 = e % 58;
        int k4 = c4 * 4;
        int r = r2 & 31, hfsel = r2 >> 5;      // 0 -> A1s, 1 -> A2s
        int n = r >> 3, t = r & 7;
        int pl = hfsel ? t : t - 1;
        short4 v = {0, 0, 0, 0};
        if (pl >= 0 && pl <= 6 && k4 < LQ) {
            const short* src = Pm + (size_t)(hfsel * NPAIR + n * 7 + pl) * PQ
                                  + (size_t)q * LQ + k4;
            v = *(const short4*)src;
        }
        *(short4*)((hfsel ? A2s : A1s) + r * APITCH + k4) = v;
    }
    __syncthreads();

    for (int i = 0; i < 3; ++i) {
        int nt = yb * 12 + wave * 3 + i;
        int c0 = nt * 16;
        int cn = c0 + n16;
        f32x4 acc0 = {0.f, 0.f, 0.f, 0.f}, acc1 = {0.f, 0.f, 0.f, 0.f};

        for (int ks = 0; ks < 7; ++ks) {
            int kb = ks * 32 + q4 * 8;
            short8 b1, b2;
#pragma unroll
            for (int j = 0; j < 8; ++j) {
                int o = idxs[kb + j];
                b1[j] = Wb1[o + cn];
                b2[j] = Wb2[o + cn];
            }

            short8 a10 = *(const short8*)&A1s[n16 * APITCH + kb];
            short8 a11 = *(const short8*)&A1s[(16 + n16) * APITCH + kb];
            short8 a20 = *(const short8*)&A2s[n16 * APITCH + kb];
            short8 a21 = *(const short8*)&A2s[(16 + n16) * APITCH + kb];
            acc0 = __builtin_amdgcn_mfma_f32_16x16x32_bf16(a10, b1, acc0, 0, 0, 0);
            acc0 = __builtin_amdgcn_mfma_f32_16x16x32_bf16(a20, b2, acc0, 0, 0, 0);
            acc1 = __builtin_amdgcn_mfma_f32_16x16x32_bf16(a11, b1, acc1, 0, 0, 0);
            acc1 = __builtin_amdgcn_mfma_f32_16x16x32_bf16(a21, b2, acc1, 0, 0, 0);
        }

#pragma unroll
        for (int mt = 0; mt < 2; ++mt) {
            f32x4 a = mt ? acc1 : acc0;
#pragma unroll
            for (int r = 0; r < 4; ++r) {
                int row = mt * 16 + q4 * 4 + r;     // = n*8 + t
                Out[(size_t)(row * 197 + 1 + q) * CC + cn] = a[r];
            }
        }
    }
}

// ---------------------------------------------------------------------------
extern "C" void kernel_launch(void* const* d_in, const int* in_sizes, int n_in,
                              void* d_out, int out_size, void* d_ws, size_t ws_size,
                              hipStream_t stream) {
    const float* Q  = (const float*)d_in[0];
    const float* K  = (const float*)d_in[1];
    const float* W1 = (const float*)d_in[2];
    const float* W2 = (const float*)d_in[3];
    float* Out = (float*)d_out;
    short* Pm = (short*)d_ws;                 // 4.3 MB
    short* Wb = (short*)d_ws + WB_OFF;        // 2.24 MB

    hipLaunchKernelGGL(attn_fused_kernel, dim3(2 * NPAIR * 7), dim3(256), 0, stream,
                       Q, K, W1, W2, Wb, Pm, Out);
    hipLaunchKernelGGL(out_mfma_kernel, dim3(196, 4), dim3(256), 0, stream,
                       Pm, Wb, Out);
}

// Round 2
// 152.983 us; speedup vs baseline: 1.4027x; 1.4027x over previous
//
#include <hip/hip_runtime.h>
#include <hip/hip_bf16.h>
#include <math.h>

// Problem constants
#define LQ 196      // spatial tokens (14x14)
#define NH 12       // heads
#define DH 64       // head dim
#define CC 768      // output channels
#define NPAIR 28    // 4 n * 7 t' pairs per half
#define PQ ((size_t)LQ * LQ)   // 38416
#define NW 729      // (2*14-1)^2 w rows

#define KROWS2 224  // 14*16 (k padded so both k-halves run 7 uniform tiles)
#define LPITCH 72   // shorts per Ks LDS row (64 + 8 pad)
#define APITCH 232  // out-kernel A LDS pitch

// ws layout (in shorts): Pm | Wb   (Qb/Kb eliminated — attn reads f32 direct)
#define PM_SHORTS ((size_t)2 * NPAIR * PQ)
#define WB_OFF    PM_SHORTS

typedef short short8 __attribute__((ext_vector_type(8)));
typedef float f32x4  __attribute__((ext_vector_type(4)));

__device__ __forceinline__ short f2bf(float f) {
    __hip_bfloat16 h = __float2bfloat16(f);
    return __builtin_bit_cast(short, h);
}

__device__ __forceinline__ short8 cvt8(float4 a, float4 b) {
    short8 r;
    r[0] = f2bf(a.x); r[1] = f2bf(a.y); r[2] = f2bf(a.z); r[3] = f2bf(a.w);
    r[4] = f2bf(b.x); r[5] = f2bf(b.y); r[6] = f2bf(b.z); r[7] = f2bf(b.w);
    return r;
}

// ---------------------------------------------------------------------------
// ATTN fused over heads, DOUBLE-BUFFERED, reading Q/K f32 directly.
// R1 lesson: LDS (76 KB) caps occupancy at 2 blocks/CU = 2 waves/SIMD, so
// the per-wave VGPR budget is 256 — but __launch_bounds__(256) alone let the
// allocator target ~104 VGPRs, which cannot hold the 72-reg f32 prefetch
// (spill/sink => 118 us, 85% stall). (256, 2) matches the allocator to the
// occupancy LDS already forces, restoring the in-register double-buffer.
// XCD swizzle: all 7 q-group blocks of a plane share blockIdx%8 -> same XCD
// -> K f32 hot-set ~1.2 MB fits 4 MB L2.
__global__ __launch_bounds__(256, 2) void attn_fused_kernel(
    const float* __restrict__ Q, const float* __restrict__ K,
    const float* __restrict__ W1, const float* __restrict__ W2,
    short* __restrict__ Wb, short* __restrict__ Pm, float* __restrict__ Out)
{
    int bid = blockIdx.x, tid = threadIdx.x;

    // --- folded prep: W -> bf16 (3 quads/thread) + zero Out l=0 rows ---
    {
        int gid = bid * 256 + tid;                    // < 100352
        const int N4 = NW * CC / 4;                   // 139968
        for (int e4 = gid; e4 < 2 * N4; e4 += 392 * 256) {
            const float* src = (e4 < N4) ? (W1 + (size_t)e4 * 4)
                                         : (W2 + (size_t)(e4 - N4) * 4);
            float4 f = *(const float4*)src;
            short4 v = {f2bf(f.x), f2bf(f.y), f2bf(f.z), f2bf(f.w)};
            *(short4*)(Wb + (size_t)e4 * 4) = v;
        }
        if (gid < 32 * CC)
            Out[(size_t)(gid / CC) * 197 * CC + (gid % CC)] = 0.f;
    }

    int xcd  = bid & 7;
    int slot = bid >> 3;
    int plane = xcd + 8 * (slot / 7);    // 0..55 = hf*28 + p
    int qg    = slot % 7;
    int p  = plane % NPAIR;
    int hf = plane / NPAIR;              // 0: (q[t+1],k[t])  1: (q[t],k[t+1])
    int n = p / 7, i = p % 7;
    int tq = hf ? i     : i + 1;
    int tk = hf ? i + 1 : i;

    __shared__ __align__(16) short Ks[2][KROWS2 * LPITCH];  // 64.5 KB
    __shared__ __align__(16) short Ps[32 * LQ];             // 12.25 KB
    __shared__ float red[2][2][2][16];                      // [h&1][strip][khalf][row]

    int wave = tid >> 6, lane = tid & 63;
    int m16  = lane & 15, q4 = lane >> 4;
    int strip = wave >> 1, khalf = wave & 1;
    int tb = khalf * 7;                  // wave's k-tile base

    // f32 bases at l=1 (row stride NH*DH = 768 floats, head stride 64)
    const float* Qf = Q + (size_t)((n * 8 + tq) * 197 + 1) * (NH * DH);
    const float* Kf = K + (size_t)((n * 8 + tk) * 197 + 1) * (NH * DH);

    int qrow = qg * 32 + strip * 16 + m16;
    int qr = (qrow < LQ) ? qrow : (LQ - 1);   // clamp; rows >=196 never stored
    const float* qbase = Qf + (size_t)qr * (NH * DH) + q4 * 8;

    // per-thread staging geometry: e = tid + 256*j
    // src row r stride = 768 f32 (heads interleaved); LDS row = LPITCH shorts
    int srf[7], sw[7];  bool sv[7];
#pragma unroll
    for (int j = 0; j < 7; ++j) {
        int e = tid + 256 * j;
        int r = e >> 3, c8 = e & 7;
        srf[j] = r * (NH * DH) + c8 * 8;     // f32 element offset from head base
        sw[j]  = r * LPITCH + c8 * 8;        // LDS offset (shorts)
        sv[j]  = (r < LQ);
    }

    float4 z4 = {0.f, 0.f, 0.f, 0.f};
    // stage h=0 (f32 load -> bf16 convert -> LDS)
#pragma unroll
    for (int j = 0; j < 7; ++j) {
        float4 a = sv[j] ? *(const float4*)(Kf + srf[j])     : z4;
        float4 b = sv[j] ? *(const float4*)(Kf + srf[j] + 4) : z4;
        *(short8*)&Ks[0][sw[j]] = cvt8(a, b);
    }
    short8 qa0 = cvt8(*(const float4*)(qbase),      *(const float4*)(qbase + 4));
    short8 qa1 = cvt8(*(const float4*)(qbase + 32), *(const float4*)(qbase + 36));
    __syncthreads();

    f32x4 pm[7];
#pragma unroll
    for (int t = 0; t < 7; ++t) pm[t] = (f32x4){0.f, 0.f, 0.f, 0.f};

    for (int h = 0; h < NH; ++h) {
        int cur = h & 1;

        // prefetch next head (f32) into VGPRs (overlaps compute below)
        float4 pfa[7], pfb[7], qn0a, qn0b, qn1a, qn1b;
        if (h < NH - 1) {
            const float* kn = Kf + (size_t)(h + 1) * DH;
#pragma unroll
            for (int j = 0; j < 7; ++j) {
                pfa[j] = sv[j] ? *(const float4*)(kn + srf[j])     : z4;
                pfb[j] = sv[j] ? *(const float4*)(kn + srf[j] + 4) : z4;
            }
            const float* qn = qbase + (size_t)(h + 1) * DH;
            qn0a = *(const float4*)(qn);
            qn0b = *(const float4*)(qn + 4);
            qn1a = *(const float4*)(qn + 32);
            qn1b = *(const float4*)(qn + 36);
        }

        // MFMA on current buffer
        f32x4 acc[7];
#pragma unroll
        for (int t = 0; t < 7; ++t) acc[t] = (f32x4){0.f, 0.f, 0.f, 0.f};
#pragma unroll
        for (int t = 0; t < 7; ++t) {
            const short* kp = &Ks[cur][((tb + t) * 16 + m16) * LPITCH + q4 * 8];
            short8 b0 = *(const short8*)(kp);
            short8 b1 = *(const short8*)(kp + 32);
            acc[t] = __builtin_amdgcn_mfma_f32_16x16x32_bf16(qa0, b0, acc[t], 0, 0, 0);
            acc[t] = __builtin_amdgcn_mfma_f32_16x16x32_bf16(qa1, b1, acc[t], 0, 0, 0);
        }

        // exp (no max-sub: logits ~N(0,1)) + wave-partial row sums
        float v4[4] = {0.f, 0.f, 0.f, 0.f};
#pragma unroll
        for (int t = 0; t < 7; ++t) {
            int k = (tb + t) * 16 + m16;
#pragma unroll
            for (int r = 0; r < 4; ++r) {
                float pe = (k < LQ) ? __expf(acc[t][r] * 0.125f) : 0.f;
                acc[t][r] = pe;
                v4[r] += pe;
            }
        }
#pragma unroll
        for (int r = 0; r < 4; ++r) {
            v4[r] += __shfl_xor(v4[r], 1, 64);
            v4[r] += __shfl_xor(v4[r], 2, 64);
            v4[r] += __shfl_xor(v4[r], 4, 64);
            v4[r] += __shfl_xor(v4[r], 8, 64);
        }
        if (m16 == 0) {
#pragma unroll
            for (int r = 0; r < 4; ++r) red[cur][strip][khalf][q4 * 4 + r] = v4[r];
        }

        // commit prefetch: vmcnt wait inserted here by compiler, then convert
        // in-reg and write the other buffer
        if (h < NH - 1) {
#pragma unroll
            for (int j = 0; j < 7; ++j)
                *(short8*)&Ks[1 - cur][sw[j]] = cvt8(pfa[j], pfb[j]);
        }
        __syncthreads();
        // safe: all Ks[cur] reads happened before this barrier; next head's
        // writes to Ks[cur] occur after it. red[cur] read below; next head
        // writes red[1-cur].

        float inv[4];
#pragma unroll
        for (int r = 0; r < 4; ++r)
            inv[r] = 1.0f / (12.0f * (red[cur][strip][0][q4 * 4 + r] +
                                      red[cur][strip][1][q4 * 4 + r]));
#pragma unroll
        for (int t = 0; t < 7; ++t)
#pragma unroll
            for (int r = 0; r < 4; ++r) pm[t][r] += acc[t][r] * inv[r];

        if (h < NH - 1) { qa0 = cvt8(qn0a, qn0b); qa1 = cvt8(qn1a, qn1b); }
    }

    // epilogue: pm -> Ps strip -> linear coalesced stores
#pragma unroll
    for (int t = 0; t < 7; ++t) {
        int k = (tb + t) * 16 + m16;
        if (k < LQ) {
#pragma unroll
            for (int r = 0; r < 4; ++r)
                Ps[(strip * 16 + q4 * 4 + r) * LQ + k] = f2bf(pm[t][r]);
        }
    }
    __syncthreads();

    int row0 = qg * 32;
    int rows = LQ - row0; if (rows > 32) rows = 32;    // qg=6 -> 4 rows
    int nb = rows * (LQ * 2);                          // bytes, mult of 16
    char* dst = (char*)(Pm + (size_t)plane * PQ + (size_t)row0 * LQ);
    const char* sp = (const char*)Ps;
    for (int e = tid * 16; e < nb; e += 256 * 16)
        *(short8*)(dst + e) = *(const short8*)(sp + e);
}

// ---------------------------------------------------------------------------
// OUT (MFMA): per q: Out[n*8+t][c] = sum_k A1[n*7+t-1][q][k]*W1[idx(q,k)][c]
//                                  + sum_k A2[n*7+t  ][q][k]*W2[idx(q,k)][c]
// T-shifted A staging (M=32, one acc set); B gathered from bf16 Wb via
// premultiplied LDS idx table. grid (196, 4): y = c-quarter (12 tiles of 16,
// 3 per wave).
__global__ __launch_bounds__(256) void out_mfma_kernel(
    const short* __restrict__ Pm, const short* __restrict__ Wb,
    float* __restrict__ Out)
{
    int q   = blockIdx.x;
    int yb  = blockIdx.y;
    int tid = threadIdx.x;
    int wave = tid >> 6, lane = tid & 63;
    int n16 = lane & 15, q4 = lane >> 4;

    __shared__ __align__(16) short A1s[32 * APITCH];   // 14.8 KB
    __shared__ __align__(16) short A2s[32 * APITCH];
    __shared__ int idxs[224];                          // premultiplied by CC

    const short* Wb1 = Wb;
    const short* Wb2 = Wb + (size_t)NW * CC;

    int pi = q / 14, pj = q % 14;
    for (int k = tid; k < 224; k += 256) {
        int v = 0;
        if (k < LQ) { int ki = k / 14, kj = k % 14; v = (pi - ki + 13) * 27 + (pj - kj + 13); }
        idxs[k] = v * CC;
    }

    // A staging: 64 rows x 58 short4 slots (APITCH=232)
    for (int e = tid; e < 64 * 58; e += 256) {
        int r2 = e / 58, c4 = e % 58;
        int k4 = c4 * 4;
        int r = r2 & 31, hfsel = r2 >> 5;      // 0 -> A1s, 1 -> A2s
        int n = r >> 3, t = r & 7;
        int pl = hfsel ? t : t - 1;
        short4 v = {0, 0, 0, 0};
        if (pl >= 0 && pl <= 6 && k4 < LQ) {
            const short* src = Pm + (size_t)(hfsel * NPAIR + n * 7 + pl) * PQ
                                  + (size_t)q * LQ + k4;
            v = *(const short4*)src;
        }
        *(short4*)((hfsel ? A2s : A1s) + r * APITCH + k4) = v;
    }
    __syncthreads();

    for (int i = 0; i < 3; ++i) {
        int nt = yb * 12 + wave * 3 + i;
        int c0 = nt * 16;
        int cn = c0 + n16;
        f32x4 acc0 = {0.f, 0.f, 0.f, 0.f}, acc1 = {0.f, 0.f, 0.f, 0.f};

        for (int ks = 0; ks < 7; ++ks) {
            int kb = ks * 32 + q4 * 8;
            short8 b1, b2;
#pragma unroll
            for (int j = 0; j < 8; ++j) {
                int o = idxs[kb + j];
                b1[j] = Wb1[o + cn];
                b2[j] = Wb2[o + cn];
            }

            short8 a10 = *(const short8*)&A1s[n16 * APITCH + kb];
            short8 a11 = *(const short8*)&A1s[(16 + n16) * APITCH + kb];
            short8 a20 = *(const short8*)&A2s[n16 * APITCH + kb];
            short8 a21 = *(const short8*)&A2s[(16 + n16) * APITCH + kb];
            acc0 = __builtin_amdgcn_mfma_f32_16x16x32_bf16(a10, b1, acc0, 0, 0, 0);
            acc0 = __builtin_amdgcn_mfma_f32_16x16x32_bf16(a20, b2, acc0, 0, 0, 0);
            acc1 = __builtin_amdgcn_mfma_f32_16x16x32_bf16(a11, b1, acc1, 0, 0, 0);
            acc1 = __builtin_amdgcn_mfma_f32_16x16x32_bf16(a21, b2, acc1, 0, 0, 0);
        }

#pragma unroll
        for (int mt = 0; mt < 2; ++mt) {
            f32x4 a = mt ? acc1 : acc0;
#pragma unroll
            for (int r = 0; r < 4; ++r) {
                int row = mt * 16 + q4 * 4 + r;     // = n*8 + t
                Out[(size_t)(row * 197 + 1 + q) * CC + cn] = a[r];
            }
        }
    }
}

// ---------------------------------------------------------------------------
extern "C" void kernel_launch(void* const* d_in, const int* in_sizes, int n_in,
                              void* d_out, int out_size, void* d_ws, size_t ws_size,
                              hipStream_t stream) {
    const float* Q  = (const float*)d_in[0];
    const float* K  = (const float*)d_in[1];
    const float* W1 = (const float*)d_in[2];
    const float* W2 = (const float*)d_in[3];
    float* Out = (float*)d_out;
    short* Pm = (short*)d_ws;                 // 4.3 MB
    short* Wb = (short*)d_ws + WB_OFF;        // 2.24 MB

    hipLaunchKernelGGL(attn_fused_kernel, dim3(2 * NPAIR * 7), dim3(256), 0, stream,
                       Q, K, W1, W2, Wb, Pm, Out);
    hipLaunchKernelGGL(out_mfma_kernel, dim3(196, 4), dim3(256), 0, stream,
                       Pm, Wb, Out);
}